// Round 1
// baseline (379.673 us; speedup 1.0000x reference)
//
#include <hip/hip_runtime.h>
#include <math.h>

// CFE hydrologic scan, fully fused.
// Layout: x_phy (T,B,2) f32; phy_static (B, 13*16+2) f32; out (T,B,1) f32.
// One thread per (b, m) chain; 16 lanes = one basin; shfl-reduce q_sim over m;
// 15-tap routing convolution done in registers with a statically-unrolled ring.

constexpr int T_STEPS = 730;
constexpr int BATCH   = 2048;
constexpr int NMULC   = 16;
constexpr int LENFC   = 15;
constexpr int NPHYS   = 13;
constexpr int NSTAT   = NPHYS * NMULC + 2; // 210
constexpr float NZ    = 1e-5f;

__global__ __launch_bounds__(64)
void cfe_kernel(const float* __restrict__ x,   // (T,B,2)
                const float* __restrict__ ps,  // (B,NSTAT)
                float* __restrict__ out)       // (T,B)
{
    const int tid = blockIdx.x * 64 + threadIdx.x;
    const int b   = tid >> 4;
    const int m   = tid & 15;
    if (b >= BATCH) return;

    const float* __restrict__ row = ps + b * NSTAT;

    // ---- parameter de-normalization: raw*(ub-lb)+lb --------------------
    const float schaake    = row[ 0*NMULC + m] * 0.1f;
    const float smcmax     = row[ 1*NMULC + m] * 0.3f   + 0.3f;
    const float soil_depth = row[ 2*NMULC + m] * 2.5f   + 0.5f;
    const float wltsmc     = row[ 3*NMULC + m] * 0.15f  + 0.05f;
    const float satpsi     = row[ 4*NMULC + m] * 0.49f  + 0.01f;
    const float bb         = row[ 5*NMULC + m] * 10.0f  + 2.0f;
    const float multp      = row[ 6*NMULC + m] * 1900.0f+ 100.0f;
    const float satdk      = row[ 7*NMULC + m] * (1e-4f - 1e-7f) + 1e-7f;
    const float slop       = row[ 8*NMULC + m];
    const float max_gw     = row[ 9*NMULC + m] * 0.49f  + 0.01f;
    const float Cgw        = row[10*NMULC + m] * (1e-3f - 1e-6f) + 1e-6f;
    const float expon      = row[11*NMULC + m] * 7.0f   + 1.0f;
    const float K          = row[12*NMULC + m] * 0.49f  + 0.01f;

    const float rout_a = row[NPHYS*NMULC + 0] * 2.9f;
    const float rout_b = row[NPHYS*NMULC + 1] * 6.5f;

    // ---- derived per-chain constants -----------------------------------
    const float inv_sd   = 1.0f / soil_depth;
    const float bud_den  = 1.0f / (smcmax - wltsmc + NZ);
    const float max_soil = smcmax * soil_depth;
    float fc_frac = powf(satpsi * inv_sd, 1.0f / bb);
    fc_frac = fminf(fmaxf(fc_frac, 0.0f), 1.0f);
    const float fc_th    = smcmax * fc_frac * soil_depth;
    const float ic       = 1.0f - expf(-schaake);          // TIMESTEP_D = 1
    const float sm       = satdk * multp;                  // * TIMESTEP_D
    const float sml      = sm * slop;
    const float inv_mft  = 1.0f / fmaxf(max_soil - fc_th, NZ);
    const float inv_mgw  = 1.0f / max_gw;

    // ---- routing weights (gamma kernel); Gamma(a)*th^a cancels under
    // normalization, so skip lgamma. Fold the 1/16 mean into w. ----------
    const float a  = fmaxf(rout_a, 0.0f) + 0.1f;
    const float th = fmaxf(rout_b, 0.0f) + 0.5f;
    float w[LENFC];
    float wsum = 0.0f;
    #pragma unroll
    for (int j = 0; j < LENFC; ++j) {
        const float tj = (float)j + 0.5f;
        w[j] = powf(tj, a - 1.0f) * expf(-tj / th);
        wsum += w[j];
    }
    const float wscale = 1.0f / (wsum * (float)NMULC);
    #pragma unroll
    for (int j = 0; j < LENFC; ++j) w[j] *= wscale;

    // ---- state ---------------------------------------------------------
    float soil = 0.05f, gw = 0.01f;
    float n0 = NZ, n1 = NZ, n2 = NZ;
    float ring[LENFC];
    #pragma unroll
    for (int j = 0; j < LENFC; ++j) ring[j] = 0.0f;

    const float2* __restrict__ xp = (const float2*)x; // (T,B) of float2

    // prefetch 2 timesteps ahead to hide HBM/L2 latency under compute
    float2 f0 = xp[0 * BATCH + b];
    float2 f1 = xp[1 * BATCH + b];

    for (int t = 0; t < T_STEPS; ++t) {
        const float p   = f0.x;
        const float pet = f0.y;
        f0 = f1;
        if (t + 2 < T_STEPS) f1 = xp[(t + 2) * BATCH + b];

        // -- ET from rain
        const float et_rain = fminf(p, pet);
        const float p_rem0  = p - et_rain;
        const float pet_rem = pet - et_rain;

        // -- soil ET (Budyko-ish)
        const float smc     = soil * inv_sd;
        float budyko = (smc - wltsmc) * bud_den;
        budyko = fminf(fmaxf(budyko, 0.0f), 1.0f);
        const float aet_soil = fminf(pet_rem * budyko, fmaxf(soil - NZ, 0.0f));
        soil -= aet_soil;

        // -- Schaake partitioning
        const float deficit   = fmaxf(max_soil - soil, 0.0f);
        const float infil_cap = deficit * ic;
        float runoff = p_rem0 * p_rem0 / (p_rem0 + infil_cap + NZ);
        runoff = fminf(runoff, p_rem0);
        const float infiltration = fminf(p_rem0 - runoff, deficit);
        runoff = p_rem0 - infiltration;
        soil += infiltration;

        // -- percolation / lateral
        const float above = fmaxf(soil - fc_th, 0.0f);
        const float frac  = above * inv_mft;
        float perc = sm  * frac;
        float lat  = sml * frac;
        const float tot   = perc + lat;
        const float scale = fminf(1.0f, above / fmaxf(tot, NZ));
        perc *= scale;
        lat  *= scale;
        soil -= perc + lat;

        // -- groundwater
        gw += perc;
        float ratio = gw * inv_mgw;
        ratio = fminf(fmaxf(ratio, 0.0f), 1.0f);
        float q_gw = Cgw * expm1f(expon * ratio);
        q_gw = fminf(fmaxf(q_gw, 0.0f), fmaxf(gw - NZ, 0.0f));
        gw -= q_gw;

        // -- 3-reservoir Nash cascade
        const float s0 = n0 + lat; const float o0 = K * s0; n0 = s0 - o0;
        const float s1 = n1 + o0;  const float o1 = K * s1; n1 = s1 - o1;
        const float s2 = n2 + o1;  const float o2 = K * s2; n2 = s2 - o2;

        float q = runoff + o2 + q_gw;

        // -- mean over the 16 multipliers (sum; 1/16 folded into w)
        q += __shfl_xor(q, 1);
        q += __shfl_xor(q, 2);
        q += __shfl_xor(q, 4);
        q += __shfl_xor(q, 8);

        // -- 15-tap routing convolution, register ring buffer
        #pragma unroll
        for (int j = LENFC - 1; j > 0; --j) ring[j] = ring[j - 1];
        ring[0] = q;
        float s = 0.0f;
        #pragma unroll
        for (int j = 0; j < LENFC; ++j) s = fmaf(w[j], ring[j], s);

        if (m == 0) out[t * BATCH + b] = s;
    }
}

extern "C" void kernel_launch(void* const* d_in, const int* in_sizes, int n_in,
                              void* d_out, int out_size, void* d_ws, size_t ws_size,
                              hipStream_t stream) {
    const float* x_phy      = (const float*)d_in[0];
    const float* phy_static = (const float*)d_in[1];
    float* out = (float*)d_out;

    const int total = BATCH * NMULC;            // 32768 threads
    const int block = 64;
    const int grid  = total / block;            // 512 blocks -> 2 per CU
    cfe_kernel<<<grid, block, 0, stream>>>(x_phy, phy_static, out);
}

// Round 2
// 292.278 us; speedup vs baseline: 1.2990x; 1.2990x over previous
//
#include <hip/hip_runtime.h>
#include <math.h>

// CFE hydrologic scan, fully fused, latency-optimized.
// One thread per (b,m) chain; 16 lanes = one basin.
// Key structure vs R1: the m-reduction (4-stage shfl butterfly) is moved OFF
// the recurrence. Each lane keeps a ring of its OWN q and convolves it
// (conv is linear, so sum-of-convs == conv-of-sum); only the conv output s
// is reduced, and that reduction is software-pipelined one step behind so
// its ~200-cycle ds-permute latency hides under the next step's ALU chain.
// Divides -> v_rcp_f32, expm1f -> __expf-1 (error budget: threshold 0.38,
// R1 measured 0.0625 with exact ops).

constexpr int T_STEPS = 730;
constexpr int BATCH   = 2048;
constexpr int NMULC   = 16;
constexpr int LENFC   = 15;
constexpr int NPHYS   = 13;
constexpr int NSTAT   = NPHYS * NMULC + 2; // 210
constexpr float NZ    = 1e-5f;

__device__ __forceinline__ float frcp(float x) { return __builtin_amdgcn_rcpf(x); }

__global__ __launch_bounds__(64, 1)
void cfe_kernel(const float* __restrict__ x,   // (T,B,2)
                const float* __restrict__ ps,  // (B,NSTAT)
                float* __restrict__ out)       // (T,B)
{
    const int tid = blockIdx.x * 64 + threadIdx.x;
    const int b   = tid >> 4;
    const int m   = tid & 15;
    if (b >= BATCH) return;

    const float* __restrict__ row = ps + b * NSTAT;

    // ---- parameter de-normalization: raw*(ub-lb)+lb --------------------
    const float schaake    = row[ 0*NMULC + m] * 0.1f;
    const float smcmax     = row[ 1*NMULC + m] * 0.3f   + 0.3f;
    const float soil_depth = row[ 2*NMULC + m] * 2.5f   + 0.5f;
    const float wltsmc     = row[ 3*NMULC + m] * 0.15f  + 0.05f;
    const float satpsi     = row[ 4*NMULC + m] * 0.49f  + 0.01f;
    const float bb         = row[ 5*NMULC + m] * 10.0f  + 2.0f;
    const float multp      = row[ 6*NMULC + m] * 1900.0f+ 100.0f;
    const float satdk      = row[ 7*NMULC + m] * (1e-4f - 1e-7f) + 1e-7f;
    const float slop       = row[ 8*NMULC + m];
    const float max_gw     = row[ 9*NMULC + m] * 0.49f  + 0.01f;
    const float Cgw        = row[10*NMULC + m] * (1e-3f - 1e-6f) + 1e-6f;
    const float expon      = row[11*NMULC + m] * 7.0f   + 1.0f;
    const float K          = row[12*NMULC + m] * 0.49f  + 0.01f;

    const float rout_a = row[NPHYS*NMULC + 0] * 2.9f;
    const float rout_b = row[NPHYS*NMULC + 1] * 6.5f;

    // ---- derived per-chain constants -----------------------------------
    const float inv_sd   = 1.0f / soil_depth;
    const float bud_den  = 1.0f / (smcmax - wltsmc + NZ);
    const float max_soil = smcmax * soil_depth;
    float fc_frac = powf(satpsi * inv_sd, 1.0f / bb);
    fc_frac = fminf(fmaxf(fc_frac, 0.0f), 1.0f);
    const float fc_th    = smcmax * fc_frac * soil_depth;
    const float ic       = 1.0f - expf(-schaake);          // TIMESTEP_D = 1
    const float sm       = satdk * multp;                  // * TIMESTEP_D
    const float sml      = sm * slop;
    const float inv_mft  = 1.0f / fmaxf(max_soil - fc_th, NZ);
    const float inv_mgw  = 1.0f / max_gw;

    // ---- routing weights (gamma kernel); Gamma(a)*th^a cancels under
    // normalization, so skip lgamma. Fold the 1/16 mean into w. ----------
    const float a  = fmaxf(rout_a, 0.0f) + 0.1f;
    const float th = fmaxf(rout_b, 0.0f) + 0.5f;
    float w[LENFC];
    float wsum = 0.0f;
    #pragma unroll
    for (int j = 0; j < LENFC; ++j) {
        const float tj = (float)j + 0.5f;
        w[j] = powf(tj, a - 1.0f) * expf(-tj / th);
        wsum += w[j];
    }
    const float wscale = 1.0f / (wsum * (float)NMULC);
    #pragma unroll
    for (int j = 0; j < LENFC; ++j) w[j] *= wscale;

    // ---- state ---------------------------------------------------------
    float soil = 0.05f, gw = 0.01f;
    float n0 = NZ, n1 = NZ, n2 = NZ;
    float ring[LENFC];                 // lane-local q history (un-reduced)
    #pragma unroll
    for (int j = 0; j < LENFC; ++j) ring[j] = 0.0f;

    const float2* __restrict__ xp = (const float2*)x; // (T,B) of float2

    float2 f0 = xp[0 * BATCH + b];
    float2 f1 = xp[1 * BATCH + b];

    float s_prev = 0.0f;               // lane-local conv output of step t-1

    #pragma unroll 2
    for (int t = 0; t < T_STEPS; ++t) {
        // ---- pipelined reduction + store for step t-1 (independent of
        // the chain below; scheduler hides the 4 ds round-trips) ---------
        {
            float r = s_prev;
            r += __shfl_xor(r, 1);
            r += __shfl_xor(r, 2);
            r += __shfl_xor(r, 4);
            r += __shfl_xor(r, 8);
            if (t > 0 && m == 0) out[(t - 1) * BATCH + b] = r;
        }

        const float p   = f0.x;
        const float pet = f0.y;
        f0 = f1;
        const int tn = (t + 2 < T_STEPS) ? (t + 2) : (T_STEPS - 1);
        f1 = xp[tn * BATCH + b];

        // -- ET from rain
        const float et_rain = fminf(p, pet);
        const float p_rem0  = p - et_rain;
        const float pet_rem = pet - et_rain;

        // -- soil ET
        const float smc     = soil * inv_sd;
        float budyko = (smc - wltsmc) * bud_den;
        budyko = fminf(fmaxf(budyko, 0.0f), 1.0f);
        const float aet_soil = fminf(pet_rem * budyko, fmaxf(soil - NZ, 0.0f));
        soil -= aet_soil;

        // -- Schaake partitioning (fast rcp instead of IEEE divide)
        const float deficit   = fmaxf(max_soil - soil, 0.0f);
        const float infil_cap = deficit * ic;
        float runoff = p_rem0 * p_rem0 * frcp(p_rem0 + infil_cap + NZ);
        runoff = fminf(runoff, p_rem0);
        const float infiltration = fminf(p_rem0 - runoff, deficit);
        runoff = p_rem0 - infiltration;
        soil += infiltration;

        // -- percolation / lateral
        const float above = fmaxf(soil - fc_th, 0.0f);
        const float frac  = above * inv_mft;
        float perc = sm  * frac;
        float lat  = sml * frac;
        const float tot   = perc + lat;
        const float scale = fminf(1.0f, above * frcp(fmaxf(tot, NZ)));
        perc *= scale;
        lat  *= scale;
        soil -= perc + lat;

        // -- groundwater (fast exp)
        gw += perc;
        float ratio = gw * inv_mgw;
        ratio = fminf(fmaxf(ratio, 0.0f), 1.0f);
        float q_gw = Cgw * (__expf(expon * ratio) - 1.0f);
        q_gw = fminf(fmaxf(q_gw, 0.0f), fmaxf(gw - NZ, 0.0f));
        gw -= q_gw;

        // -- 3-reservoir Nash cascade
        const float s0 = n0 + lat; const float o0 = K * s0; n0 = s0 - o0;
        const float s1 = n1 + o0;  const float o1 = K * s1; n1 = s1 - o1;
        const float s2 = n2 + o1;  const float o2 = K * s2; n2 = s2 - o2;

        const float q = runoff + o2 + q_gw;   // lane-local, NOT reduced

        // -- 15-tap conv on lane-local history (treed, 4 partial sums)
        #pragma unroll
        for (int j = LENFC - 1; j > 0; --j) ring[j] = ring[j - 1];
        ring[0] = q;
        float c0 = 0.0f, c1 = 0.0f, c2 = 0.0f, c3 = 0.0f;
        #pragma unroll
        for (int j = 0; j < LENFC; j += 4) {
            c0 = fmaf(w[j], ring[j], c0);
            if (j + 1 < LENFC) c1 = fmaf(w[j + 1], ring[j + 1], c1);
            if (j + 2 < LENFC) c2 = fmaf(w[j + 2], ring[j + 2], c2);
            if (j + 3 < LENFC) c3 = fmaf(w[j + 3], ring[j + 3], c3);
        }
        s_prev = (c0 + c1) + (c2 + c3);
    }

    // ---- epilogue: reduce + store the final step -----------------------
    {
        float r = s_prev;
        r += __shfl_xor(r, 1);
        r += __shfl_xor(r, 2);
        r += __shfl_xor(r, 4);
        r += __shfl_xor(r, 8);
        if (m == 0) out[(T_STEPS - 1) * BATCH + b] = r;
    }
}

extern "C" void kernel_launch(void* const* d_in, const int* in_sizes, int n_in,
                              void* d_out, int out_size, void* d_ws, size_t ws_size,
                              hipStream_t stream) {
    const float* x_phy      = (const float*)d_in[0];
    const float* phy_static = (const float*)d_in[1];
    float* out = (float*)d_out;

    const int total = BATCH * NMULC;            // 32768 threads
    const int block = 64;
    const int grid  = total / block;            // 512 blocks -> 2 per CU
    cfe_kernel<<<grid, block, 0, stream>>>(x_phy, phy_static, out);
}

// Round 3
// 282.148 us; speedup vs baseline: 1.3457x; 1.0359x over previous
//
#include <hip/hip_runtime.h>
#include <math.h>

// CFE hydrologic scan, fully fused, latency-optimized (R3).
// One thread per (b,m) chain; 16 lanes = one basin.
// R3 change: the 16-lane m-reduction is done with DPP16 row ops
// (quad_perm xor1/xor2, row_half_mirror, row_mirror) -- pure VALU, no LDS,
// no lgkmcnt waits. The kernel now contains zero DS instructions.
// Also: percolation algebra folded (tot = c*above), redundant clamps
// dropped (soil<=max_soil invariant; runoff<=p_rem algebraically),
// expon*log2e prefolded into the gw exponential.

constexpr int T_STEPS = 730;
constexpr int BATCH   = 2048;
constexpr int NMULC   = 16;
constexpr int LENFC   = 15;
constexpr int NPHYS   = 13;
constexpr int NSTAT   = NPHYS * NMULC + 2; // 210
constexpr float NZ    = 1e-5f;

__device__ __forceinline__ float frcp(float x) { return __builtin_amdgcn_rcpf(x); }

// 16-lane sum via DPP16: xor1, xor2, half-mirror (quad swap), mirror (octet
// swap). All lanes end with the full 16-lane sum. No LDS involved.
__device__ __forceinline__ float dpp_sum16(float x) {
    int v;
    v = __builtin_amdgcn_update_dpp(0, __float_as_int(x), 0xB1, 0xF, 0xF, true); // quad_perm(1,0,3,2)
    x += __int_as_float(v);
    v = __builtin_amdgcn_update_dpp(0, __float_as_int(x), 0x4E, 0xF, 0xF, true); // quad_perm(2,3,0,1)
    x += __int_as_float(v);
    v = __builtin_amdgcn_update_dpp(0, __float_as_int(x), 0x141, 0xF, 0xF, true); // row_half_mirror
    x += __int_as_float(v);
    v = __builtin_amdgcn_update_dpp(0, __float_as_int(x), 0x140, 0xF, 0xF, true); // row_mirror
    x += __int_as_float(v);
    return x;
}

__global__ __launch_bounds__(64, 1)
void cfe_kernel(const float* __restrict__ x,   // (T,B,2)
                const float* __restrict__ ps,  // (B,NSTAT)
                float* __restrict__ out)       // (T,B)
{
    const int tid = blockIdx.x * 64 + threadIdx.x;
    const int b   = tid >> 4;
    const int m   = tid & 15;
    if (b >= BATCH) return;

    const float* __restrict__ row = ps + b * NSTAT;

    // ---- parameter de-normalization: raw*(ub-lb)+lb --------------------
    const float schaake    = row[ 0*NMULC + m] * 0.1f;
    const float smcmax     = row[ 1*NMULC + m] * 0.3f   + 0.3f;
    const float soil_depth = row[ 2*NMULC + m] * 2.5f   + 0.5f;
    const float wltsmc     = row[ 3*NMULC + m] * 0.15f  + 0.05f;
    const float satpsi     = row[ 4*NMULC + m] * 0.49f  + 0.01f;
    const float bb         = row[ 5*NMULC + m] * 10.0f  + 2.0f;
    const float multp      = row[ 6*NMULC + m] * 1900.0f+ 100.0f;
    const float satdk      = row[ 7*NMULC + m] * (1e-4f - 1e-7f) + 1e-7f;
    const float slop       = row[ 8*NMULC + m];
    const float max_gw     = row[ 9*NMULC + m] * 0.49f  + 0.01f;
    const float Cgw        = row[10*NMULC + m] * (1e-3f - 1e-6f) + 1e-6f;
    const float expon      = row[11*NMULC + m] * 7.0f   + 1.0f;
    const float K          = row[12*NMULC + m] * 0.49f  + 0.01f;

    const float rout_a = row[NPHYS*NMULC + 0] * 2.9f;
    const float rout_b = row[NPHYS*NMULC + 1] * 6.5f;

    // ---- derived per-chain constants -----------------------------------
    const float inv_sd   = 1.0f / soil_depth;
    const float bud_den  = 1.0f / (smcmax - wltsmc + NZ);
    const float max_soil = smcmax * soil_depth;
    float fc_frac = powf(satpsi * inv_sd, 1.0f / bb);
    fc_frac = fminf(fmaxf(fc_frac, 0.0f), 1.0f);
    const float fc_th    = smcmax * fc_frac * soil_depth;
    const float ic       = 1.0f - expf(-schaake);          // TIMESTEP_D = 1
    const float sm       = satdk * multp;                  // * TIMESTEP_D
    const float sml      = sm * slop;
    const float inv_mft  = 1.0f / fmaxf(max_soil - fc_th, NZ);
    const float inv_mgw  = 1.0f / max_gw;
    // folded percolation coefficients: tot = c*above; perc = pc*asc; lat = lc*asc
    const float cc  = inv_mft * (sm + sml);
    const float pc  = sm  * inv_mft;
    const float lc  = sml * inv_mft;
    const float e2  = expon * 1.442695041f;                // expon * log2(e)

    // ---- routing weights (gamma kernel); Gamma(a)*th^a cancels under
    // normalization, so skip lgamma. Fold the 1/16 mean into w. ----------
    const float a  = fmaxf(rout_a, 0.0f) + 0.1f;
    const float th = fmaxf(rout_b, 0.0f) + 0.5f;
    float w[LENFC];
    float wsum = 0.0f;
    #pragma unroll
    for (int j = 0; j < LENFC; ++j) {
        const float tj = (float)j + 0.5f;
        w[j] = powf(tj, a - 1.0f) * expf(-tj / th);
        wsum += w[j];
    }
    const float wscale = 1.0f / (wsum * (float)NMULC);
    #pragma unroll
    for (int j = 0; j < LENFC; ++j) w[j] *= wscale;

    // ---- state ---------------------------------------------------------
    float soil = 0.05f, gw = 0.01f;
    float n0 = NZ, n1 = NZ, n2 = NZ;
    float ring[LENFC];                 // lane-local q history (un-reduced)
    #pragma unroll
    for (int j = 0; j < LENFC; ++j) ring[j] = 0.0f;

    const float2* __restrict__ xp = (const float2*)x; // (T,B) of float2

    float2 f0 = xp[0 * BATCH + b];
    float2 f1 = xp[1 * BATCH + b];

    float s_prev = 0.0f;               // lane-local conv output of step t-1

    #pragma unroll 2
    for (int t = 0; t < T_STEPS; ++t) {
        // ---- pipelined DPP reduction + store for step t-1 (pure VALU,
        // hangs off s_prev only; store feeds nothing) --------------------
        {
            const float r = dpp_sum16(s_prev);
            if (t > 0 && m == 0) out[(t - 1) * BATCH + b] = r;
        }

        const float p   = f0.x;
        const float pet = f0.y;
        f0 = f1;
        const int tn = (t + 2 < T_STEPS) ? (t + 2) : (T_STEPS - 1);
        f1 = xp[tn * BATCH + b];

        // -- ET from rain
        const float et_rain = fminf(p, pet);
        const float p_rem0  = p - et_rain;
        const float pet_rem = pet - et_rain;

        // -- soil ET
        const float smc     = soil * inv_sd;
        float budyko = (smc - wltsmc) * bud_den;
        budyko = fminf(fmaxf(budyko, 0.0f), 1.0f);
        const float aet_soil = fminf(pet_rem * budyko, fmaxf(soil - NZ, 0.0f));
        soil -= aet_soil;

        // -- Schaake partitioning (soil <= max_soil invariant: no clamp)
        const float deficit   = max_soil - soil;
        const float infil_cap = deficit * ic;
        const float runoff0   = p_rem0 * p_rem0 * frcp(p_rem0 + infil_cap + NZ);
        const float infiltration = fminf(p_rem0 - runoff0, deficit);
        const float runoff = p_rem0 - infiltration;
        soil += infiltration;

        // -- percolation / lateral (folded: tot = cc*above)
        const float above = fmaxf(soil - fc_th, 0.0f);
        const float totc  = cc * above;
        const float scale = fminf(1.0f, above * frcp(fmaxf(totc, NZ)));
        const float asc   = above * scale;
        const float lat   = lc * asc;
        soil -= cc * asc;              // perc + lat

        // -- groundwater (exp2-based expm1)
        gw += pc * asc;                // + perc
        float ratio = gw * inv_mgw;
        ratio = fminf(fmaxf(ratio, 0.0f), 1.0f);
        float q_gw = Cgw * (__builtin_amdgcn_exp2f(e2 * ratio) - 1.0f);
        q_gw = fminf(fmaxf(q_gw, 0.0f), fmaxf(gw - NZ, 0.0f));
        gw -= q_gw;

        // -- 3-reservoir Nash cascade
        const float s0 = n0 + lat; const float o0 = K * s0; n0 = s0 - o0;
        const float s1 = n1 + o0;  const float o1 = K * s1; n1 = s1 - o1;
        const float s2 = n2 + o1;  const float o2 = K * s2; n2 = s2 - o2;

        const float q = runoff + o2 + q_gw;   // lane-local, NOT reduced

        // -- 15-tap conv on lane-local history (treed, 4 partial sums)
        #pragma unroll
        for (int j = LENFC - 1; j > 0; --j) ring[j] = ring[j - 1];
        ring[0] = q;
        float c0 = 0.0f, c1 = 0.0f, c2 = 0.0f, c3 = 0.0f;
        #pragma unroll
        for (int j = 0; j < LENFC; j += 4) {
            c0 = fmaf(w[j], ring[j], c0);
            if (j + 1 < LENFC) c1 = fmaf(w[j + 1], ring[j + 1], c1);
            if (j + 2 < LENFC) c2 = fmaf(w[j + 2], ring[j + 2], c2);
            if (j + 3 < LENFC) c3 = fmaf(w[j + 3], ring[j + 3], c3);
        }
        s_prev = (c0 + c1) + (c2 + c3);
    }

    // ---- epilogue: reduce + store the final step -----------------------
    {
        const float r = dpp_sum16(s_prev);
        if (m == 0) out[(T_STEPS - 1) * BATCH + b] = r;
    }
}

extern "C" void kernel_launch(void* const* d_in, const int* in_sizes, int n_in,
                              void* d_out, int out_size, void* d_ws, size_t ws_size,
                              hipStream_t stream) {
    const float* x_phy      = (const float*)d_in[0];
    const float* phy_static = (const float*)d_in[1];
    float* out = (float*)d_out;

    const int total = BATCH * NMULC;            // 32768 threads
    const int block = 64;
    const int grid  = total / block;            // 512 blocks -> 2 per CU
    cfe_kernel<<<grid, block, 0, stream>>>(x_phy, phy_static, out);
}